// Round 8
// baseline (164.001 us; speedup 1.0000x reference)
//
#include <hip/hip_runtime.h>
#include <stdint.h>

#define D_MODEL 1024
#define T_LEN   4096
#define B_SZ    4
#define NROWS   (B_SZ * T_LEN)   // 16384
#define NPROJ   (2 * D_MODEL)    // 2048
#define CHUNK   32               // rows of T per k_post block

#define BM 256
#define BN 256
#define BK 64
#define NT (D_MODEL / BK)        // 16 K-steps

typedef __attribute__((ext_vector_type(8))) __bf16 bf16x8;
typedef __attribute__((ext_vector_type(4))) float  f32x4;

using as1_void = __attribute__((address_space(1))) void;
using as3_void = __attribute__((address_space(3))) void;

__device__ inline float bf2f(unsigned short u) {
    union { unsigned int i; float f; } v; v.i = ((unsigned int)u) << 16; return v.f;
}
__device__ inline unsigned short f2bf(float f) {
    union { float f; unsigned int i; } v; v.f = f;
    return (unsigned short)((v.i + 0x7fffu + ((v.i >> 16) & 1u)) >> 16);
}
__device__ inline float sigmoidf(float x) { return 1.0f / (1.0f + __expf(-x)); }

// ---------------- K0: fused converts (x fp32->bf16, W fp32->bf16 transposed) ----------------
__global__ __launch_bounds__(256) void k_cvt(const float* __restrict__ x,
                                             unsigned short* __restrict__ xb,
                                             const float* __restrict__ W,
                                             unsigned short* __restrict__ wt) {
    __shared__ unsigned short tile[32][33];
    int bid = blockIdx.x;
    if (bid < (NROWS * D_MODEL) / (256 * 4)) {
        int i = (bid * 256 + threadIdx.x) * 4;
        float4 v = *reinterpret_cast<const float4*>(x + i);
        ushort4 o;
        o.x = f2bf(v.x); o.y = f2bf(v.y); o.z = f2bf(v.z); o.w = f2bf(v.w);
        *reinterpret_cast<ushort4*>(xb + i) = o;
    } else {
        bid -= (NROWS * D_MODEL) / (256 * 4);
        int n0 = (bid & 63) * 32, k0 = (bid >> 6) * 32;
        int c = threadIdx.x & 31, r = threadIdx.x >> 5;  // r in 0..7
        #pragma unroll
        for (int i = 0; i < 4; i++) {
            int kk = r + i * 8;
            tile[kk][c] = f2bf(W[(uint64_t)(k0 + kk) * NPROJ + n0 + c]);
        }
        __syncthreads();
        #pragma unroll
        for (int i = 0; i < 4; i++) {
            int nn = r + i * 8;
            wt[(uint64_t)(n0 + nn) * D_MODEL + k0 + c] = tile[c][nn];
        }
    }
}

// ---------------- K1: GEMM proj = xb @ wt^T + bias, store bf16 ----------------
// EXACT R3 kernel (verified 85.6us x3 runs, 0 bank conflicts). DO NOT touch
// the epilogue: any branch/extra math there perturbs the K-loop schedule
// (R5: +31us, R6: +14us).
__global__ __launch_bounds__(512, 2) void k_gemm(const unsigned short* __restrict__ xb,
                                                 const unsigned short* __restrict__ wt,
                                                 const float* __restrict__ bias,
                                                 unsigned short* __restrict__ projb) {
    __shared__ __align__(16) unsigned short As[2 * BM * BK];  // 64 KB
    __shared__ __align__(16) unsigned short Bs[2 * BM * BK];  // 64 KB

    const int tid  = threadIdx.x;
    const int lane = tid & 63;
    const int w    = tid >> 6;       // wave 0..7
    const int wm   = w >> 2;         // 0..1  (M half)
    const int wn   = w & 3;          // 0..3  (N quarter)

    // T1: 512 blocks = 8 n-tiles x 64 m-tiles; XCD k owns n-column k.
    const int bid = blockIdx.x;
    const int wg  = (bid & 7) * 64 + (bid >> 3);
    const int n0  = (wg >> 6) * BN;
    const int m0  = (wg & 63) * BM;

    const int srow = tid >> 3;                        // LDS row (mod 64) this thread fills
    const int scol = ((tid & 7) ^ (srow & 7)) * 8;    // T2: inverse-swizzled global col
    const int fr   = lane & 15;
    const int fq   = lane >> 4;

    f32x4 acc[8][4] = {};

    auto STAGE = [&](int buf, int ks) {
        #pragma unroll
        for (int i = 0; i < 4; ++i) {
            const unsigned short* ga = xb + (uint64_t)(m0 + i * 64 + srow) * D_MODEL + ks + scol;
            __builtin_amdgcn_global_load_lds((as1_void*)(void*)ga,
                (as3_void*)(void*)&As[buf * (BM * BK) + i * 4096 + w * 512], 16, 0, 0);
        }
        #pragma unroll
        for (int i = 0; i < 4; ++i) {
            const unsigned short* gb = wt + (uint64_t)(n0 + i * 64 + srow) * D_MODEL + ks + scol;
            __builtin_amdgcn_global_load_lds((as1_void*)(void*)gb,
                (as3_void*)(void*)&Bs[buf * (BM * BK) + i * 4096 + w * 512], 16, 0, 0);
        }
    };

    STAGE(0, 0);
    __syncthreads();

    for (int t = 0; t < NT; ++t) {
        const int cur = t & 1;
        if (t + 1 < NT) STAGE(1 - cur, (t + 1) * BK);   // issue-first prefetch

        const unsigned short* Ab = &As[cur * (BM * BK)];
        const unsigned short* Bb = &Bs[cur * (BM * BK)];
        #pragma unroll
        for (int kk = 0; kk < BK; kk += 32) {
            const int slot = (kk >> 3) + fq;            // global k-octet
            bf16x8 b[4];
            #pragma unroll
            for (int n = 0; n < 4; n++) {
                const int rb = wn * 64 + n * 16 + fr;
                b[n] = *reinterpret_cast<const bf16x8*>(&Bb[rb * 64 + ((slot ^ (fr & 7)) * 8)]);
            }
            #pragma unroll
            for (int m = 0; m < 8; m++) {
                const int ra = wm * 128 + m * 16 + fr;
                bf16x8 a = *reinterpret_cast<const bf16x8*>(&Ab[ra * 64 + ((slot ^ (fr & 7)) * 8)]);
                #pragma unroll
                for (int n = 0; n < 4; n++)
                    acc[m][n] = __builtin_amdgcn_mfma_f32_16x16x32_bf16(a, b[n], acc[m][n], 0, 0, 0);
            }
        }
        __syncthreads();
    }

    // epilogue: D layout col=lane&15, row=(lane>>4)*4+reg  [verified m89/m91]
    #pragma unroll
    for (int m = 0; m < 8; m++) {
        const int grow = m0 + wm * 128 + m * 16 + fq * 4;
        #pragma unroll
        for (int n = 0; n < 4; n++) {
            const int gcol = n0 + wn * 64 + n * 16 + fr;
            const float bv = bias[gcol];
            #pragma unroll
            for (int r = 0; r < 4; r++) {
                projb[(uint64_t)(grow + r) * NPROJ + gcol] = f2bf(acc[m][n][r] + bv);
            }
        }
    }
}

// ---------------- K1b: in-place RoPE on the x_a half of projb ----------------
// thread = 4 pairs (8 channels, 16B). Fully coalesced; cos/sin read ONCE
// (not once per batch per halo as in the old k_post). 80MB total ~= 13us.
__global__ __launch_bounds__(256) void k_rope(unsigned short* __restrict__ projb,
                                              const float* __restrict__ sinp,
                                              const float* __restrict__ cosp) {
    const uint64_t u  = (uint64_t)blockIdx.x * 256 + threadIdx.x; // unit = 4 pairs
    const int row = (int)(u >> 7);          // 128 units per row
    const int c0  = ((int)u & 127) * 4;     // first pair index
    const int t   = row & (T_LEN - 1);

    unsigned int* p = reinterpret_cast<unsigned int*>(projb + (uint64_t)row * NPROJ + c0 * 2);
    uint4  v  = *reinterpret_cast<const uint4*>(p);
    float4 cc = *reinterpret_cast<const float4*>(cosp + (uint64_t)t * (D_MODEL / 2) + c0);
    float4 ss = *reinterpret_cast<const float4*>(sinp + (uint64_t)t * (D_MODEL / 2) + c0);

    auto rot = [&](unsigned int w, float cv, float sv) -> unsigned int {
        float x0 = bf2f((unsigned short)(w & 0xffffu));
        float x1 = bf2f((unsigned short)(w >> 16));
        float r0 = x0 * cv - x1 * sv;
        float r1 = x0 * sv + x1 * cv;
        return (unsigned int)f2bf(r0) | ((unsigned int)f2bf(r1) << 16);
    };
    uint4 o;
    o.x = rot(v.x, cc.x, ss.x);
    o.y = rot(v.y, cc.y, ss.y);
    o.z = rot(v.z, cc.z, ss.z);
    o.w = rot(v.w, cc.w, ss.w);
    *reinterpret_cast<uint4*>(p) = o;
}

// ---------------- K2: conv7 + SiLU + sigmoid-gate + RMSNorm (x_a pre-rotated) ----------------
__global__ __launch_bounds__(512) void k_post(const unsigned short* __restrict__ projb,
                                              const float* __restrict__ kw,
                                              const float* __restrict__ dwb,
                                              const float* __restrict__ gamma,
                                              float* __restrict__ out) {
    const int blk  = blockIdx.x;
    const int b    = blk / (T_LEN / CHUNK);
    const int t0   = (blk % (T_LEN / CHUNK)) * CHUNK;
    const int c    = threadIdx.x;          // channel-pair index 0..511
    const int d0   = c * 2;
    const uint64_t bbase = (uint64_t)b * T_LEN;

    float kwv[7][2];
    #pragma unroll
    for (int j = 0; j < 7; j++) {
        kwv[j][0] = kw[j * D_MODEL + d0];
        kwv[j][1] = kw[j * D_MODEL + d0 + 1];
    }
    const float bv0 = dwb[d0], bv1 = dwb[d0 + 1];
    const float gm0 = gamma[d0], gm1 = gamma[d0 + 1];

    __shared__ float red[2][8];

    auto load_row = [&](int tj, float& o0, float& o1) {
        if ((unsigned)tj < (unsigned)T_LEN) {
            ushort2 u = *reinterpret_cast<const ushort2*>(projb + (bbase + tj) * NPROJ + d0);
            o0 = bf2f(u.x); o1 = bf2f(u.y);
        } else { o0 = 0.f; o1 = 0.f; }
    };

    float rg[6][2];
    #pragma unroll
    for (int j = 0; j < 6; j++) load_row(t0 - 3 + j, rg[j][0], rg[j][1]);
    float nx0, nx1;
    load_row(t0 + 3, nx0, nx1);

    ushort2 xb_cur = *reinterpret_cast<const ushort2*>(projb + (bbase + t0) * NPROJ + D_MODEL + d0);

    for (int t = t0; t < t0 + CHUNK; ++t) {
        const float r60 = nx0, r61 = nx1;

        float acc0 = rg[0][0] * kwv[0][0] + rg[1][0] * kwv[1][0] + rg[2][0] * kwv[2][0]
                   + rg[3][0] * kwv[3][0] + rg[4][0] * kwv[4][0] + rg[5][0] * kwv[5][0]
                   + r60 * kwv[6][0] + bv0;
        float acc1 = rg[0][1] * kwv[0][1] + rg[1][1] * kwv[1][1] + rg[2][1] * kwv[2][1]
                   + rg[3][1] * kwv[3][1] + rg[4][1] * kwv[4][1] + rg[5][1] * kwv[5][1]
                   + r61 * kwv[6][1] + bv1;

        load_row(t + 4, nx0, nx1);
        const ushort2 xb_use = xb_cur;
        if (t + 1 < t0 + CHUNK) {
            xb_cur = *reinterpret_cast<const ushort2*>(projb + (bbase + t + 1) * NPROJ + D_MODEL + d0);
        }

        // SiLU(conv) * sigmoid(x_b)
        float a0 = acc0 * sigmoidf(acc0);
        float a1 = acc1 * sigmoidf(acc1);
        float g0 = a0 * sigmoidf(bf2f(xb_use.x));
        float g1 = a1 * sigmoidf(bf2f(xb_use.y));

        float ssq = g0 * g0 + g1 * g1;
        #pragma unroll
        for (int off = 32; off; off >>= 1) ssq += __shfl_down(ssq, off);
        const int p = t & 1;
        if ((threadIdx.x & 63) == 0) red[p][threadIdx.x >> 6] = ssq;
        __syncthreads();
        float total = red[p][0] + red[p][1] + red[p][2] + red[p][3]
                    + red[p][4] + red[p][5] + red[p][6] + red[p][7];
        const float inv = 1.0f / sqrtf(total * (1.0f / (float)D_MODEL) + 1e-8f);

        float2 o;
        o.x = g0 * inv * gm0;
        o.y = g1 * inv * gm1;
        *reinterpret_cast<float2*>(out + (bbase + t) * D_MODEL + d0) = o;

        #pragma unroll
        for (int j = 0; j < 5; j++) { rg[j][0] = rg[j + 1][0]; rg[j][1] = rg[j + 1][1]; }
        rg[5][0] = r60; rg[5][1] = r61;
    }
}

extern "C" void kernel_launch(void* const* d_in, const int* in_sizes, int n_in,
                              void* d_out, int out_size, void* d_ws, size_t ws_size,
                              hipStream_t stream) {
    const float* x     = (const float*)d_in[0];
    const float* sinp  = (const float*)d_in[1];
    const float* cosp  = (const float*)d_in[2];
    const float* W     = (const float*)d_in[3];
    const float* bproj = (const float*)d_in[4];
    const float* dwk   = (const float*)d_in[5];
    const float* dwb   = (const float*)d_in[6];
    const float* gamma = (const float*)d_in[7];
    float* out = (float*)d_out;

    unsigned short* xb    = (unsigned short*)d_ws;                       // 32 MB
    unsigned short* wt    = xb + (size_t)NROWS * D_MODEL;                // 4 MB
    unsigned short* projb = wt + (size_t)NPROJ * D_MODEL;                // 64 MB

    const int cvt_x_blocks = (NROWS * D_MODEL) / (256 * 4);              // 16384
    const int cvt_w_blocks = (NPROJ / 32) * (D_MODEL / 32);              // 2048
    k_cvt<<<cvt_x_blocks + cvt_w_blocks, 256, 0, stream>>>(x, xb, W, wt);
    k_gemm<<<(NPROJ / BN) * (NROWS / BM), 512, 0, stream>>>(xb, wt, bproj, projb);
    k_rope<<<(NROWS * 128) / 256, 256, 0, stream>>>(projb, sinp, cosp);
    k_post<<<B_SZ * (T_LEN / CHUNK), 512, 0, stream>>>(projb, dwk, dwb, gamma, out);
}

// Round 9
// 151.844 us; speedup vs baseline: 1.0801x; 1.0801x over previous
//
#include <hip/hip_runtime.h>
#include <stdint.h>

#define D_MODEL 1024
#define T_LEN   4096
#define B_SZ    4
#define NROWS   (B_SZ * T_LEN)   // 16384
#define NPROJ   (2 * D_MODEL)    // 2048
#define CHUNK   16               // rows of T per k_post block (all 4 batches)

#define BM 256
#define BN 256
#define BK 64
#define NT (D_MODEL / BK)        // 16 K-steps

typedef __attribute__((ext_vector_type(8))) __bf16 bf16x8;
typedef __attribute__((ext_vector_type(4))) float  f32x4;

using as1_void = __attribute__((address_space(1))) void;
using as3_void = __attribute__((address_space(3))) void;

__device__ inline float bf2f(unsigned short u) {
    union { unsigned int i; float f; } v; v.i = ((unsigned int)u) << 16; return v.f;
}
__device__ inline unsigned short f2bf(float f) {
    union { float f; unsigned int i; } v; v.f = f;
    return (unsigned short)((v.i + 0x7fffu + ((v.i >> 16) & 1u)) >> 16);
}
__device__ inline float sigmoidf(float x) { return 1.0f / (1.0f + __expf(-x)); }

// ---------------- K0: fused converts (x fp32->bf16, W fp32->bf16 transposed) ----------------
__global__ __launch_bounds__(256) void k_cvt(const float* __restrict__ x,
                                             unsigned short* __restrict__ xb,
                                             const float* __restrict__ W,
                                             unsigned short* __restrict__ wt) {
    __shared__ unsigned short tile[32][33];
    int bid = blockIdx.x;
    if (bid < (NROWS * D_MODEL) / (256 * 4)) {
        int i = (bid * 256 + threadIdx.x) * 4;
        float4 v = *reinterpret_cast<const float4*>(x + i);
        ushort4 o;
        o.x = f2bf(v.x); o.y = f2bf(v.y); o.z = f2bf(v.z); o.w = f2bf(v.w);
        *reinterpret_cast<ushort4*>(xb + i) = o;
    } else {
        bid -= (NROWS * D_MODEL) / (256 * 4);
        int n0 = (bid & 63) * 32, k0 = (bid >> 6) * 32;
        int c = threadIdx.x & 31, r = threadIdx.x >> 5;  // r in 0..7
        #pragma unroll
        for (int i = 0; i < 4; i++) {
            int kk = r + i * 8;
            tile[kk][c] = f2bf(W[(uint64_t)(k0 + kk) * NPROJ + n0 + c]);
        }
        __syncthreads();
        #pragma unroll
        for (int i = 0; i < 4; i++) {
            int nn = r + i * 8;
            wt[(uint64_t)(n0 + nn) * D_MODEL + k0 + c] = tile[c][nn];
        }
    }
}

// ---------------- K1: GEMM proj = xb @ wt^T + bias, store bf16 ----------------
// EXACT R3 kernel (verified 85.6us x4 runs, 0 bank conflicts). DO NOT touch
// the epilogue: any branch/extra math there perturbs the K-loop schedule
// (R5: +31us, R6: +14us).
__global__ __launch_bounds__(512, 2) void k_gemm(const unsigned short* __restrict__ xb,
                                                 const unsigned short* __restrict__ wt,
                                                 const float* __restrict__ bias,
                                                 unsigned short* __restrict__ projb) {
    __shared__ __align__(16) unsigned short As[2 * BM * BK];  // 64 KB
    __shared__ __align__(16) unsigned short Bs[2 * BM * BK];  // 64 KB

    const int tid  = threadIdx.x;
    const int lane = tid & 63;
    const int w    = tid >> 6;       // wave 0..7
    const int wm   = w >> 2;         // 0..1  (M half)
    const int wn   = w & 3;          // 0..3  (N quarter)

    // T1: 512 blocks = 8 n-tiles x 64 m-tiles; XCD k owns n-column k.
    const int bid = blockIdx.x;
    const int wg  = (bid & 7) * 64 + (bid >> 3);
    const int n0  = (wg >> 6) * BN;
    const int m0  = (wg & 63) * BM;

    const int srow = tid >> 3;                        // LDS row (mod 64) this thread fills
    const int scol = ((tid & 7) ^ (srow & 7)) * 8;    // T2: inverse-swizzled global col
    const int fr   = lane & 15;
    const int fq   = lane >> 4;

    f32x4 acc[8][4] = {};

    auto STAGE = [&](int buf, int ks) {
        #pragma unroll
        for (int i = 0; i < 4; ++i) {
            const unsigned short* ga = xb + (uint64_t)(m0 + i * 64 + srow) * D_MODEL + ks + scol;
            __builtin_amdgcn_global_load_lds((as1_void*)(void*)ga,
                (as3_void*)(void*)&As[buf * (BM * BK) + i * 4096 + w * 512], 16, 0, 0);
        }
        #pragma unroll
        for (int i = 0; i < 4; ++i) {
            const unsigned short* gb = wt + (uint64_t)(n0 + i * 64 + srow) * D_MODEL + ks + scol;
            __builtin_amdgcn_global_load_lds((as1_void*)(void*)gb,
                (as3_void*)(void*)&Bs[buf * (BM * BK) + i * 4096 + w * 512], 16, 0, 0);
        }
    };

    STAGE(0, 0);
    __syncthreads();

    for (int t = 0; t < NT; ++t) {
        const int cur = t & 1;
        if (t + 1 < NT) STAGE(1 - cur, (t + 1) * BK);   // issue-first prefetch

        const unsigned short* Ab = &As[cur * (BM * BK)];
        const unsigned short* Bb = &Bs[cur * (BM * BK)];
        #pragma unroll
        for (int kk = 0; kk < BK; kk += 32) {
            const int slot = (kk >> 3) + fq;            // global k-octet
            bf16x8 b[4];
            #pragma unroll
            for (int n = 0; n < 4; n++) {
                const int rb = wn * 64 + n * 16 + fr;
                b[n] = *reinterpret_cast<const bf16x8*>(&Bb[rb * 64 + ((slot ^ (fr & 7)) * 8)]);
            }
            #pragma unroll
            for (int m = 0; m < 8; m++) {
                const int ra = wm * 128 + m * 16 + fr;
                bf16x8 a = *reinterpret_cast<const bf16x8*>(&Ab[ra * 64 + ((slot ^ (fr & 7)) * 8)]);
                #pragma unroll
                for (int n = 0; n < 4; n++)
                    acc[m][n] = __builtin_amdgcn_mfma_f32_16x16x32_bf16(a, b[n], acc[m][n], 0, 0, 0);
            }
        }
        __syncthreads();
    }

    // epilogue: D layout col=lane&15, row=(lane>>4)*4+reg  [verified m89/m91]
    #pragma unroll
    for (int m = 0; m < 8; m++) {
        const int grow = m0 + wm * 128 + m * 16 + fq * 4;
        #pragma unroll
        for (int n = 0; n < 4; n++) {
            const int gcol = n0 + wn * 64 + n * 16 + fr;
            const float bv = bias[gcol];
            #pragma unroll
            for (int r = 0; r < 4; r++) {
                projb[(uint64_t)(grow + r) * NPROJ + gcol] = f2bf(acc[m][n][r] + bv);
            }
        }
    }
}

// ---------------- K2: batch-fused RoPE + conv7 + SiLU + gate + RMSNorm ----------------
// One block owns CHUNK rows of T for ALL 4 batches: cos/sin loaded once per tap
// (not per batch), 4 independent load/compute chains per iteration (ILP hides
// HBM latency), one barrier serves 4 RMS reductions.
__global__ __launch_bounds__(512) void k_post(const unsigned short* __restrict__ projb,
                                              const float* __restrict__ sinp,
                                              const float* __restrict__ cosp,
                                              const float* __restrict__ kw,
                                              const float* __restrict__ dwb,
                                              const float* __restrict__ gamma,
                                              float* __restrict__ out) {
    const int t0 = blockIdx.x * CHUNK;
    const int c  = threadIdx.x;          // channel-pair index 0..511
    const int d0 = c * 2;

    float kwv[7][2];
    #pragma unroll
    for (int j = 0; j < 7; j++) {
        kwv[j][0] = kw[j * D_MODEL + d0];
        kwv[j][1] = kw[j * D_MODEL + d0 + 1];
    }
    const float bv0 = dwb[d0], bv1 = dwb[d0 + 1];
    const float gm0 = gamma[d0], gm1 = gamma[d0 + 1];

    __shared__ f32x4 red[2][8];   // [parity][wave] -> per-batch partial ssq

    // load + rope one tap row for all 4 batches; zero outside [0,T)
    auto load_tap = [&](int tj, float (&o)[B_SZ][2]) {
        if ((unsigned)tj < (unsigned)T_LEN) {
            const float cv = cosp[(uint64_t)tj * (D_MODEL / 2) + c];
            const float sv = sinp[(uint64_t)tj * (D_MODEL / 2) + c];
            #pragma unroll
            for (int b = 0; b < B_SZ; b++) {
                ushort2 u = *reinterpret_cast<const ushort2*>(
                    projb + ((uint64_t)b * T_LEN + tj) * NPROJ + d0);
                float x0 = bf2f(u.x), x1 = bf2f(u.y);
                o[b][0] = x0 * cv - x1 * sv;
                o[b][1] = x0 * sv + x1 * cv;
            }
        } else {
            #pragma unroll
            for (int b = 0; b < B_SZ; b++) { o[b][0] = 0.f; o[b][1] = 0.f; }
        }
    };
    auto load_xb = [&](int tj, ushort2 (&o)[B_SZ]) {
        #pragma unroll
        for (int b = 0; b < B_SZ; b++)
            o[b] = *reinterpret_cast<const ushort2*>(
                projb + ((uint64_t)b * T_LEN + tj) * NPROJ + D_MODEL + d0);
    };

    // ring rg[0..5] = taps t-3..t+2 ; nx = tap t+3
    float rg[6][B_SZ][2];
    #pragma unroll
    for (int j = 0; j < 6; j++) load_tap(t0 - 3 + j, rg[j]);
    float nx[B_SZ][2];
    load_tap(t0 + 3, nx);

    ushort2 xbc[B_SZ];
    load_xb(t0, xbc);

    #pragma unroll 1
    for (int t = t0; t < t0 + CHUNK; ++t) {
        const int p = t & 1;

        float g[B_SZ][2];
        float s0, s1, s2, s3;
        #pragma unroll
        for (int b = 0; b < B_SZ; b++) {
            #pragma unroll
            for (int ch = 0; ch < 2; ch++) {
                float a = rg[0][b][ch] * kwv[0][ch] + rg[1][b][ch] * kwv[1][ch]
                        + rg[2][b][ch] * kwv[2][ch] + rg[3][b][ch] * kwv[3][ch]
                        + rg[4][b][ch] * kwv[4][ch] + rg[5][b][ch] * kwv[5][ch]
                        + nx[b][ch]   * kwv[6][ch] + (ch ? bv1 : bv0);
                float sl = a * sigmoidf(a);                       // SiLU(conv)
                float xv = bf2f(ch ? xbc[b].y : xbc[b].x);
                g[b][ch] = sl * sigmoidf(xv);                     // gate
            }
        }
        s0 = g[0][0] * g[0][0] + g[0][1] * g[0][1];
        s1 = g[1][0] * g[1][0] + g[1][1] * g[1][1];
        s2 = g[2][0] * g[2][0] + g[2][1] * g[2][1];
        s3 = g[3][0] * g[3][0] + g[3][1] * g[3][1];

        // shift ring (static indices), then prefetch next tap + next x_b
        #pragma unroll
        for (int j = 0; j < 5; j++) {
            #pragma unroll
            for (int b = 0; b < B_SZ; b++) { rg[j][b][0] = rg[j + 1][b][0]; rg[j][b][1] = rg[j + 1][b][1]; }
        }
        #pragma unroll
        for (int b = 0; b < B_SZ; b++) { rg[5][b][0] = nx[b][0]; rg[5][b][1] = nx[b][1]; }
        load_tap(t + 4, nx);
        ushort2 xbu[B_SZ];
        #pragma unroll
        for (int b = 0; b < B_SZ; b++) xbu[b] = xbc[b];
        if (t + 1 < t0 + CHUNK) load_xb(t + 1, xbc);
        (void)xbu;

        // 4 independent wave reductions, single barrier
        #pragma unroll
        for (int off = 32; off; off >>= 1) {
            s0 += __shfl_down(s0, off);
            s1 += __shfl_down(s1, off);
            s2 += __shfl_down(s2, off);
            s3 += __shfl_down(s3, off);
        }
        if ((c & 63) == 0) {
            f32x4 v; v[0] = s0; v[1] = s1; v[2] = s2; v[3] = s3;
            red[p][c >> 6] = v;
        }
        __syncthreads();
        f32x4 tot = red[p][0] + red[p][1] + red[p][2] + red[p][3]
                  + red[p][4] + red[p][5] + red[p][6] + red[p][7];

        #pragma unroll
        for (int b = 0; b < B_SZ; b++) {
            const float inv = 1.0f / sqrtf(tot[b] * (1.0f / (float)D_MODEL) + 1e-8f);
            float2 o;
            o.x = g[b][0] * inv * gm0;
            o.y = g[b][1] * inv * gm1;
            *reinterpret_cast<float2*>(out + ((uint64_t)b * T_LEN + t) * D_MODEL + d0) = o;
        }
    }
}

extern "C" void kernel_launch(void* const* d_in, const int* in_sizes, int n_in,
                              void* d_out, int out_size, void* d_ws, size_t ws_size,
                              hipStream_t stream) {
    const float* x     = (const float*)d_in[0];
    const float* sinp  = (const float*)d_in[1];
    const float* cosp  = (const float*)d_in[2];
    const float* W     = (const float*)d_in[3];
    const float* bproj = (const float*)d_in[4];
    const float* dwk   = (const float*)d_in[5];
    const float* dwb   = (const float*)d_in[6];
    const float* gamma = (const float*)d_in[7];
    float* out = (float*)d_out;

    unsigned short* xb    = (unsigned short*)d_ws;                       // 32 MB
    unsigned short* wt    = xb + (size_t)NROWS * D_MODEL;                // 4 MB
    unsigned short* projb = wt + (size_t)NPROJ * D_MODEL;                // 64 MB

    const int cvt_x_blocks = (NROWS * D_MODEL) / (256 * 4);              // 16384
    const int cvt_w_blocks = (NPROJ / 32) * (D_MODEL / 32);              // 2048
    k_cvt<<<cvt_x_blocks + cvt_w_blocks, 256, 0, stream>>>(x, xb, W, wt);
    k_gemm<<<(NPROJ / BN) * (NROWS / BM), 512, 0, stream>>>(xb, wt, bproj, projb);
    k_post<<<T_LEN / CHUNK, 512, 0, stream>>>(projb, sinp, cosp, dwk, dwb, gamma, out);
}